// Round 12
// baseline (177.288 us; speedup 1.0000x reference)
//
#include <hip/hip_runtime.h>
#include <hip/hip_bf16.h>

#define BB 2
#define NN 20000
#define EE 200000
#define INF 256
#define OUTF 32
#define NH 4
#define HF 128          // NH*OUTF
#define NEG_SLOPE 0.2f
#define GEMM_BLOCKS 1250 // 40000 rows / 32
#define EDGE_BLOCKS 98

using bf16 = __hip_bfloat16;
typedef __attribute__((ext_vector_type(8))) short bf16x8;
typedef __attribute__((ext_vector_type(4))) float f32x4;

__device__ __forceinline__ float bf2f(unsigned short s){ return __uint_as_float((unsigned)s << 16); }
__device__ __forceinline__ ushort f2bf_bits(float f){
    __hip_bfloat16 b = __float2bfloat16(f);
    return *(ushort*)&b;
}

__device__ __forceinline__ int get_src(const int* ei, int e, int f64){
    return f64 ? ei[2 * e] : ei[e];
}
__device__ __forceinline__ int get_dst(const int* ei, int e, int f64){
    return f64 ? ei[2 * EE + 2 * e] : ei[EE + e];
}

// K0: zero fp32 output (d_out), init last_edge; block 0 additionally does
// dtype-detect and converts W into bf16 *B-frag-linear* layout wbf:
// frag i = ((ch*8 + kc)*4 + t)*64 + lane  ->  8 shorts at wbf[i*8],
// holding W[col=ch*64+t*16+(lane&15)][k=kc*32+(lane>>4)*8 + j].
__global__ void k_init(const ushort* __restrict__ xr, const int* __restrict__ er,
                       const void* __restrict__ Wv,
                       int* __restrict__ flags, ushort* __restrict__ wbf,
                       float* __restrict__ out_f, int* __restrict__ last_e){
    int i = blockIdx.x * blockDim.x + threadIdx.x;
    if (i < BB * NN * OUTF) out_f[i] = 0.f;
    if (i < NN) last_e[i] = -1;
    if (blockIdx.x == 0){
        __shared__ int cnt_big, cnt_nz;
        if (threadIdx.x == 0){ cnt_big = 0; cnt_nz = 0; }
        __syncthreads();
        int big = 0;
        for (int k = threadIdx.x; k < 8192; k += blockDim.x){
            unsigned e = ((unsigned)xr[2 * k] >> 7) & 0xff;   // bf16-exp of fp32 low half
            if (e >= 0xC0) big++;                              // impossible for N(0,1) bf16
        }
        int nz = 0;
        for (int k = threadIdx.x; k < 4096; k += blockDim.x){
            if (er[2 * k + 1] != 0) nz++;                      // int64 high words all zero
        }
        atomicAdd(&cnt_big, big);
        atomicAdd(&cnt_nz, nz);
        __syncthreads();
        if (threadIdx.x == 0){
            flags[0] = (cnt_big >= 16) ? 1 : 0;
            flags[1] = (cnt_nz == 0) ? 1 : 0;
        }
        const bool f32w = (cnt_big >= 16);
        for (int fr = threadIdx.x; fr < 4096; fr += blockDim.x){
            int lane = fr & 63;
            int t    = (fr >> 6) & 3;
            int kc   = (fr >> 8) & 7;
            int ch   = fr >> 11;
            int col  = ch * 64 + t * 16 + (lane & 15);
            int kb   = kc * 32 + (lane >> 4) * 8;
            bf16x8 v;
            if (f32w){
                const float* wg = (const float*)Wv + (size_t)col * INF + kb;
                #pragma unroll
                for (int j = 0; j < 8; ++j) v[j] = (short)f2bf_bits(wg[j]);
            } else {
                const ushort* wg = (const ushort*)Wv + (size_t)col * INF + kb;
                #pragma unroll
                for (int j = 0; j < 8; ++j) v[j] = (short)wg[j];
            }
            *(bf16x8*)(wbf + (size_t)fr * 8) = v;
        }
    }
}

// K1: MFMA GEMM (no LDS) + alpha epilogue + fused last-edge atomicMax blocks.
// Block = 32 rows x 128 cols, 4 waves; wave = 16 rows x 64 cols (4 tiles).
// All 8 A-frag loads issued up-front for MLP; B-frags from frag-linear
// bf16 W (coalesced, L2-hot). h written f-major: h[row][f*4+hd].
__global__ __launch_bounds__(256, 4)
void k_gemm(const void* __restrict__ xv_, const ushort* __restrict__ wbf,
            const void* __restrict__ av, const int* __restrict__ ei,
            const int* __restrict__ flags, ushort* __restrict__ h,
            float* __restrict__ alpha_s, float* __restrict__ alpha_d,
            int* __restrict__ last_e){
    if (blockIdx.x >= GEMM_BLOCKS){
        int f64 = flags[1];
        int t = (blockIdx.x - GEMM_BLOCKS) * 256 + threadIdx.x;
        for (int e = t; e < EE; e += EDGE_BLOCKS * 256)
            atomicMax(&last_e[get_src(ei, e, f64)], e);
        return;
    }

    const int tid  = threadIdx.x;
    const int lane = tid & 63;
    const int w    = tid >> 6;            // wave 0..3
    const int l15  = lane & 15;
    const int q    = lane >> 4;           // quad 0..3
    const bool f32 = flags[0] != 0;

    const int row0 = blockIdx.x * 32 + (w >> 1) * 16;  // wave's 16 rows
    const int ch   = w & 1;                            // col-half
    const int hd0  = ch * 2;                           // first head (0 or 2)

    f32x4 acc[4];
    #pragma unroll
    for (int t = 0; t < 4; ++t) acc[t] = (f32x4){0.f, 0.f, 0.f, 0.f};

    const ushort* wb = wbf + (size_t)ch * 16384;       // this col-half's frags

    if (f32){
        const float* xp = (const float*)xv_ + (size_t)(row0 + l15) * INF + q * 8;
        float4 raw[8][2];
        #pragma unroll
        for (int kc = 0; kc < 8; ++kc){                // all loads in flight
            const float4* p = (const float4*)(xp + kc * 32);
            raw[kc][0] = p[0];
            raw[kc][1] = p[1];
        }
        #pragma unroll
        for (int kc = 0; kc < 8; ++kc){
            float4 lo = raw[kc][0], hi = raw[kc][1];
            bf16x8 afrag;
            afrag[0] = (short)f2bf_bits(lo.x); afrag[1] = (short)f2bf_bits(lo.y);
            afrag[2] = (short)f2bf_bits(lo.z); afrag[3] = (short)f2bf_bits(lo.w);
            afrag[4] = (short)f2bf_bits(hi.x); afrag[5] = (short)f2bf_bits(hi.y);
            afrag[6] = (short)f2bf_bits(hi.z); afrag[7] = (short)f2bf_bits(hi.w);
            #pragma unroll
            for (int t = 0; t < 4; ++t){
                bf16x8 bfrag = *(const bf16x8*)(wb + (((size_t)kc * 4 + t) * 64 + lane) * 8);
                acc[t] = __builtin_amdgcn_mfma_f32_16x16x32_bf16(afrag, bfrag, acc[t], 0, 0, 0);
            }
        }
    } else {
        const ushort* xp = (const ushort*)xv_ + (size_t)(row0 + l15) * INF + q * 8;
        #pragma unroll
        for (int kc = 0; kc < 8; ++kc){
            bf16x8 afrag = *(const bf16x8*)(xp + kc * 32);
            #pragma unroll
            for (int t = 0; t < 4; ++t){
                bf16x8 bfrag = *(const bf16x8*)(wb + (((size_t)kc * 4 + t) * 64 + lane) * 8);
                acc[t] = __builtin_amdgcn_mfma_f32_16x16x32_bf16(afrag, bfrag, acc[t], 0, 0, 0);
            }
        }
    }

    // ---- epilogue 1: h -> bf16, f-major [row][f*4+hd] ----
    // C layout: col = ch*64+t*16+l15, row = row0+q*4+reg (m89-verified).
    // Tile t: head hd0+(t>>1), f-half t&1; head-pair partner = t+2.
    #pragma unroll
    for (int r = 0; r < 4; ++r){
        int row = row0 + q * 4 + r;
        #pragma unroll
        for (int t = 0; t < 2; ++t){    // t = f-half; f = t*16 + l15
            unsigned v = (unsigned)f2bf_bits(acc[t][r])
                       | ((unsigned)f2bf_bits(acc[t + 2][r]) << 16);
            int f = t * 16 + l15;
            *(unsigned*)(h + (size_t)row * HF + f * 4 + hd0) = v;
        }
    }

    // ---- epilogue 2: alpha dots from C registers ----
    float as_lo, as_hi, ad_lo, ad_hi;
    if (f32){
        const float* af = (const float*)av;
        as_lo = af[l15];        as_hi = af[16 + l15];
        ad_lo = af[OUTF + l15]; ad_hi = af[OUTF + 16 + l15];
    } else {
        const ushort* ab = (const ushort*)av;
        as_lo = bf2f(ab[l15]);        as_hi = bf2f(ab[16 + l15]);
        ad_lo = bf2f(ab[OUTF + l15]); ad_hi = bf2f(ab[OUTF + 16 + l15]);
    }
    #pragma unroll
    for (int r = 0; r < 4; ++r){
        int row = row0 + q * 4 + r;
        #pragma unroll
        for (int hp = 0; hp < 2; ++hp){   // head = hd0+hp; tiles 2hp (f<16), 2hp+1 (f>=16)
            int t0 = hp * 2, t1 = hp * 2 + 1;
            float ps = acc[t0][r] * as_lo + acc[t1][r] * as_hi;
            float pd = acc[t0][r] * ad_lo + acc[t1][r] * ad_hi;
            ps += __shfl_down(ps, 8, 16); pd += __shfl_down(pd, 8, 16);
            ps += __shfl_down(ps, 4, 16); pd += __shfl_down(pd, 4, 16);
            ps += __shfl_down(ps, 2, 16); pd += __shfl_down(pd, 2, 16);
            ps += __shfl_down(ps, 1, 16); pd += __shfl_down(pd, 1, 16);
            if (l15 == 0){
                size_t o = (size_t)row * NH + hd0 + hp;
                alpha_s[o] = ps;
                alpha_d[o] = pd;
            }
        }
    }
}

// K2: attention weight per (b,node,head): batch softmax at last edge, /NH folded in
__global__ void k_aw(const int* __restrict__ ei, const int* __restrict__ flags,
                     const int* __restrict__ last_e,
                     const float* __restrict__ alpha_s, const float* __restrict__ alpha_d,
                     float* __restrict__ aw){
    int n = blockIdx.x * blockDim.x + threadIdx.x;
    if (n >= NN) return;
    int le = last_e[n];
    if (le < 0){
        #pragma unroll
        for (int hh = 0; hh < NH; ++hh){
            aw[((size_t)0 * NN + n) * NH + hh] = 0.f;
            aw[((size_t)1 * NN + n) * NH + hh] = 0.f;
        }
        return;
    }
    int d = get_dst(ei, le, flags[1]);
    #pragma unroll
    for (int hh = 0; hh < NH; ++hh){
        float s0 = alpha_s[((size_t)0 * NN + n) * NH + hh] + alpha_d[((size_t)0 * NN + d) * NH + hh];
        float s1 = alpha_s[((size_t)1 * NN + n) * NH + hh] + alpha_d[((size_t)1 * NN + d) * NH + hh];
        s0 = s0 > 0.f ? s0 : NEG_SLOPE * s0;
        s1 = s1 > 0.f ? s1 : NEG_SLOPE * s1;
        float m  = fmaxf(s0, s1);
        float e0 = __expf(s0 - m);
        float e1 = __expf(s1 - m);
        float inv = 1.f / (e0 + e1);
        aw[((size_t)0 * NN + n) * NH + hh] = 0.25f * e0 * inv;
        aw[((size_t)1 * NN + n) * NH + hh] = 0.25f * e1 * inv;
    }
}

// K3: edge scatter into fp32 d_out, 4 edges per wave-iteration for MLP.
// lane = b*32+f; h is f-major bf16 (4 heads per f = one 8-B load).
__global__ void k_scatter(const int* __restrict__ ei, const int* __restrict__ flags,
                          const ushort* __restrict__ h, const float* __restrict__ aw,
                          float* __restrict__ out_f){
    int lane = threadIdx.x & 63;
    int wid  = (blockIdx.x * blockDim.x + threadIdx.x) >> 6;
    int nw   = (gridDim.x * blockDim.x) >> 6;
    int b = lane >> 5;
    int f = lane & 31;
    int f64 = flags[1];
    for (int e0 = wid * 4; e0 < EE; e0 += nw * 4){
        int cnt = EE - e0; if (cnt > 4) cnt = 4;   // wave-uniform
        int s[4], d[4];
        #pragma unroll
        for (int j = 0; j < 4; ++j){
            if (j < cnt){
                s[j] = get_src(ei, e0 + j, f64);
                d[j] = get_dst(ei, e0 + j, f64);
            }
        }
        float4  awv[4];
        ushort4 u[4];
        #pragma unroll
        for (int j = 0; j < 4; ++j){
            if (j < cnt){
                awv[j] = *(const float4*)(aw + ((size_t)b * NN + s[j]) * NH);
                u[j]   = *(const ushort4*)(h + ((size_t)b * NN + d[j]) * HF + f * 4);
            }
        }
        #pragma unroll
        for (int j = 0; j < 4; ++j){
            if (j < cnt){
                float acc = awv[j].x * bf2f(u[j].x)
                          + awv[j].y * bf2f(u[j].y)
                          + awv[j].z * bf2f(u[j].z)
                          + awv[j].w * bf2f(u[j].w);
                atomicAdd(&out_f[((size_t)b * NN + s[j]) * OUTF + f], acc);
            }
        }
    }
}

extern "C" void kernel_launch(void* const* d_in, const int* in_sizes, int n_in,
                              void* d_out, int out_size, void* d_ws, size_t ws_size,
                              hipStream_t stream){
    const void* x = d_in[0]; const void* eiv = d_in[1];
    const void* W = d_in[2]; const void* a  = d_in[3];
    for (int i = 0; i < n_in; ++i){
        if      (in_sizes[i] == BB * NN * INF) x   = d_in[i];
        else if (in_sizes[i] == 2 * EE)        eiv = d_in[i];
        else if (in_sizes[i] == HF * INF)      W   = d_in[i];
        else if (in_sizes[i] == 2 * OUTF)      a   = d_in[i];
    }
    const int* ei = (const int*)eiv;
    float* out = (float*)d_out;    // output dtype: float32 (verified round 3)

    // Workspace: flags | wbf (frag-linear bf16 W, 64 KB) | h (bf16 f-major)
    //            | alpha_s | alpha_d | aw | last_e
    const size_t HN = (size_t)BB * NN * HF;
    char* p = (char*)d_ws;
    int*    flags   = (int*)p;                        p += 64;
    ushort* wbf     = (ushort*)p;                     p += 32768 * 2;
    ushort* h       = (ushort*)p;                     p += HN * 2;
    float*  alpha_s = (float*)p;                      p += (size_t)BB * NN * NH * 4;
    float*  alpha_d = (float*)p;                      p += (size_t)BB * NN * NH * 4;
    float*  aw      = (float*)p;                      p += (size_t)BB * NN * NH * 4;
    int*    last_e  = (int*)p;

    k_init   <<<(BB * NN * OUTF + 255) / 256, 256, 0, stream>>>((const ushort*)x, ei, W, flags, wbf, out, last_e);
    k_gemm   <<<GEMM_BLOCKS + EDGE_BLOCKS, 256, 0, stream>>>(x, wbf, a, ei, flags, h, alpha_s, alpha_d, last_e);
    k_aw     <<<(NN + 255) / 256, 256, 0, stream>>>(ei, flags, last_e, alpha_s, alpha_d, aw);
    k_scatter<<<2048, 256, 0, stream>>>(ei, flags, h, aw, out);
}

// Round 13
// 157.719 us; speedup vs baseline: 1.1241x; 1.1241x over previous
//
#include <hip/hip_runtime.h>
#include <hip/hip_bf16.h>

#define BB 2
#define NN 20000
#define EE 200000
#define INF 256
#define OUTF 32
#define NH 4
#define HF 128          // NH*OUTF
#define NEG_SLOPE 0.2f
#define GEMM_BLOCKS 1250 // 40000 rows / 32
#define EDGE_BLOCKS 98
#define CAP 96           // slots per node (deg ~ Poisson(10); overflow -> list)
#define OVF_CAP 8192

using bf16 = __hip_bfloat16;
typedef __attribute__((ext_vector_type(8))) short bf16x8;
typedef __attribute__((ext_vector_type(4))) float f32x4;

__device__ __forceinline__ float bf2f(unsigned short s){ return __uint_as_float((unsigned)s << 16); }
__device__ __forceinline__ ushort f2bf_bits(float f){
    __hip_bfloat16 b = __float2bfloat16(f);
    return *(ushort*)&b;
}

__device__ __forceinline__ int get_src(const int* ei, int e, int f64){
    return f64 ? ei[2 * e] : ei[e];
}
__device__ __forceinline__ int get_dst(const int* ei, int e, int f64){
    return f64 ? ei[2 * EE + 2 * e] : ei[EE + e];
}

// K0: init cnt/last_e/ovf; block 0: dtype-detect + W -> bf16 B-frag-linear wbf.
__global__ void k_init(const ushort* __restrict__ xr, const int* __restrict__ er,
                       const void* __restrict__ Wv,
                       int* __restrict__ flags, ushort* __restrict__ wbf,
                       int* __restrict__ cnt, int* __restrict__ last_e,
                       int* __restrict__ ovf_cnt){
    int i = blockIdx.x * blockDim.x + threadIdx.x;
    if (i < NN){ cnt[i] = 0; last_e[i] = -1; }
    if (i == 0) *ovf_cnt = 0;
    if (blockIdx.x == 0){
        __shared__ int cnt_big, cnt_nz;
        if (threadIdx.x == 0){ cnt_big = 0; cnt_nz = 0; }
        __syncthreads();
        int big = 0;
        for (int k = threadIdx.x; k < 8192; k += blockDim.x){
            unsigned e = ((unsigned)xr[2 * k] >> 7) & 0xff;   // bf16-exp of fp32 low half
            if (e >= 0xC0) big++;                              // impossible for N(0,1) bf16
        }
        int nz = 0;
        for (int k = threadIdx.x; k < 4096; k += blockDim.x){
            if (er[2 * k + 1] != 0) nz++;                      // int64 high words all zero
        }
        atomicAdd(&cnt_big, big);
        atomicAdd(&cnt_nz, nz);
        __syncthreads();
        if (threadIdx.x == 0){
            flags[0] = (cnt_big >= 16) ? 1 : 0;
            flags[1] = (cnt_nz == 0) ? 1 : 0;
        }
        const bool f32w = (cnt_big >= 16);
        for (int fr = threadIdx.x; fr < 4096; fr += blockDim.x){
            int lane = fr & 63;
            int t    = (fr >> 6) & 3;
            int kc   = (fr >> 8) & 7;
            int ch   = fr >> 11;
            int col  = ch * 64 + t * 16 + (lane & 15);
            int kb   = kc * 32 + (lane >> 4) * 8;
            bf16x8 v;
            if (f32w){
                const float* wg = (const float*)Wv + (size_t)col * INF + kb;
                #pragma unroll
                for (int j = 0; j < 8; ++j) v[j] = (short)f2bf_bits(wg[j]);
            } else {
                const ushort* wg = (const ushort*)Wv + (size_t)col * INF + kb;
                #pragma unroll
                for (int j = 0; j < 8; ++j) v[j] = (short)wg[j];
            }
            *(bf16x8*)(wbf + (size_t)fr * 8) = v;
        }
    }
}

// K1: MFMA GEMM + alpha epilogue; edge blocks build buckets + last_e.
__global__ __launch_bounds__(256, 4)
void k_gemm(const void* __restrict__ xv_, const ushort* __restrict__ wbf,
            const void* __restrict__ av, const int* __restrict__ ei,
            const int* __restrict__ flags, ushort* __restrict__ h,
            float* __restrict__ alpha_s, float* __restrict__ alpha_d,
            int* __restrict__ last_e, int* __restrict__ cnt,
            ushort* __restrict__ slots, int* __restrict__ ovf_cnt,
            int* __restrict__ ovf_list){
    if (blockIdx.x >= GEMM_BLOCKS){
        int f64 = flags[1];
        int t = (blockIdx.x - GEMM_BLOCKS) * 256 + threadIdx.x;
        for (int e = t; e < EE; e += EDGE_BLOCKS * 256){
            int s = get_src(ei, e, f64);
            int d = get_dst(ei, e, f64);
            atomicMax(&last_e[s], e);
            int idx = atomicAdd(&cnt[s], 1);
            if (idx < CAP) slots[(size_t)s * CAP + idx] = (ushort)d;
            else { int o = atomicAdd(ovf_cnt, 1); if (o < OVF_CAP) ovf_list[o] = e; }
        }
        return;
    }

    const int tid  = threadIdx.x;
    const int lane = tid & 63;
    const int w    = tid >> 6;            // wave 0..3
    const int l15  = lane & 15;
    const int q    = lane >> 4;           // quad 0..3
    const bool f32 = flags[0] != 0;

    const int row0 = blockIdx.x * 32 + (w >> 1) * 16;  // wave's 16 rows
    const int ch   = w & 1;                            // col-half
    const int hd0  = ch * 2;                           // first head (0 or 2)

    f32x4 acc[4];
    #pragma unroll
    for (int t = 0; t < 4; ++t) acc[t] = (f32x4){0.f, 0.f, 0.f, 0.f};

    const ushort* wb = wbf + (size_t)ch * 16384;       // this col-half's frags

    if (f32){
        const float* xp = (const float*)xv_ + (size_t)(row0 + l15) * INF + q * 8;
        float4 raw[8][2];
        #pragma unroll
        for (int kc = 0; kc < 8; ++kc){                // all loads in flight
            const float4* p = (const float4*)(xp + kc * 32);
            raw[kc][0] = p[0];
            raw[kc][1] = p[1];
        }
        #pragma unroll
        for (int kc = 0; kc < 8; ++kc){
            float4 lo = raw[kc][0], hi = raw[kc][1];
            bf16x8 afrag;
            afrag[0] = (short)f2bf_bits(lo.x); afrag[1] = (short)f2bf_bits(lo.y);
            afrag[2] = (short)f2bf_bits(lo.z); afrag[3] = (short)f2bf_bits(lo.w);
            afrag[4] = (short)f2bf_bits(hi.x); afrag[5] = (short)f2bf_bits(hi.y);
            afrag[6] = (short)f2bf_bits(hi.z); afrag[7] = (short)f2bf_bits(hi.w);
            #pragma unroll
            for (int t = 0; t < 4; ++t){
                bf16x8 bfrag = *(const bf16x8*)(wb + (((size_t)kc * 4 + t) * 64 + lane) * 8);
                acc[t] = __builtin_amdgcn_mfma_f32_16x16x32_bf16(afrag, bfrag, acc[t], 0, 0, 0);
            }
        }
    } else {
        const ushort* xp = (const ushort*)xv_ + (size_t)(row0 + l15) * INF + q * 8;
        #pragma unroll
        for (int kc = 0; kc < 8; ++kc){
            bf16x8 afrag = *(const bf16x8*)(xp + kc * 32);
            #pragma unroll
            for (int t = 0; t < 4; ++t){
                bf16x8 bfrag = *(const bf16x8*)(wb + (((size_t)kc * 4 + t) * 64 + lane) * 8);
                acc[t] = __builtin_amdgcn_mfma_f32_16x16x32_bf16(afrag, bfrag, acc[t], 0, 0, 0);
            }
        }
    }

    // ---- epilogue 1: h -> bf16, f-major [row][f*4+hd] ----
    #pragma unroll
    for (int r = 0; r < 4; ++r){
        int row = row0 + q * 4 + r;
        #pragma unroll
        for (int t = 0; t < 2; ++t){    // t = f-half; f = t*16 + l15
            unsigned v = (unsigned)f2bf_bits(acc[t][r])
                       | ((unsigned)f2bf_bits(acc[t + 2][r]) << 16);
            int f = t * 16 + l15;
            *(unsigned*)(h + (size_t)row * HF + f * 4 + hd0) = v;
        }
    }

    // ---- epilogue 2: alpha dots from C registers ----
    float as_lo, as_hi, ad_lo, ad_hi;
    if (f32){
        const float* af = (const float*)av;
        as_lo = af[l15];        as_hi = af[16 + l15];
        ad_lo = af[OUTF + l15]; ad_hi = af[OUTF + 16 + l15];
    } else {
        const ushort* ab = (const ushort*)av;
        as_lo = bf2f(ab[l15]);        as_hi = bf2f(ab[16 + l15]);
        ad_lo = bf2f(ab[OUTF + l15]); ad_hi = bf2f(ab[OUTF + 16 + l15]);
    }
    #pragma unroll
    for (int r = 0; r < 4; ++r){
        int row = row0 + q * 4 + r;
        #pragma unroll
        for (int hp = 0; hp < 2; ++hp){
            int t0 = hp * 2, t1 = hp * 2 + 1;
            float ps = acc[t0][r] * as_lo + acc[t1][r] * as_hi;
            float pd = acc[t0][r] * ad_lo + acc[t1][r] * ad_hi;
            ps += __shfl_down(ps, 8, 16); pd += __shfl_down(pd, 8, 16);
            ps += __shfl_down(ps, 4, 16); pd += __shfl_down(pd, 4, 16);
            ps += __shfl_down(ps, 2, 16); pd += __shfl_down(pd, 2, 16);
            ps += __shfl_down(ps, 1, 16); pd += __shfl_down(pd, 1, 16);
            if (l15 == 0){
                size_t o = (size_t)row * NH + hd0 + hp;
                alpha_s[o] = ps;
                alpha_d[o] = pd;
            }
        }
    }
}

// K2: attention weight per (b,node,head): batch softmax at last edge, /NH folded in
__global__ void k_aw(const int* __restrict__ ei, const int* __restrict__ flags,
                     const int* __restrict__ last_e,
                     const float* __restrict__ alpha_s, const float* __restrict__ alpha_d,
                     float* __restrict__ aw){
    int n = blockIdx.x * blockDim.x + threadIdx.x;
    if (n >= NN) return;
    int le = last_e[n];
    if (le < 0){
        #pragma unroll
        for (int hh = 0; hh < NH; ++hh){
            aw[((size_t)0 * NN + n) * NH + hh] = 0.f;
            aw[((size_t)1 * NN + n) * NH + hh] = 0.f;
        }
        return;
    }
    int d = get_dst(ei, le, flags[1]);
    #pragma unroll
    for (int hh = 0; hh < NH; ++hh){
        float s0 = alpha_s[((size_t)0 * NN + n) * NH + hh] + alpha_d[((size_t)0 * NN + d) * NH + hh];
        float s1 = alpha_s[((size_t)1 * NN + n) * NH + hh] + alpha_d[((size_t)1 * NN + d) * NH + hh];
        s0 = s0 > 0.f ? s0 : NEG_SLOPE * s0;
        s1 = s1 > 0.f ? s1 : NEG_SLOPE * s1;
        float m  = fmaxf(s0, s1);
        float e0 = __expf(s0 - m);
        float e1 = __expf(s1 - m);
        float inv = 1.f / (e0 + e1);
        aw[((size_t)0 * NN + n) * NH + hh] = 0.25f * e0 * inv;
        aw[((size_t)1 * NN + n) * NH + hh] = 0.25f * e1 * inv;
    }
}

// K3: per-node aggregate, atomic-free. One wave per node; lane = b*32+f.
// out[b,n,f] = sum_h aw[b,n,h] * (sum_{e in bucket(n)} h[b,dst_e][f*4+h])
__global__ __launch_bounds__(256)
void k_agg(const ushort* __restrict__ slots, const int* __restrict__ cnt,
           const ushort* __restrict__ h, const float* __restrict__ aw,
           float* __restrict__ out_f){
    int lane = threadIdx.x & 63;
    int wid  = (blockIdx.x * blockDim.x + threadIdx.x) >> 6;
    int nw   = (gridDim.x * blockDim.x) >> 6;
    int b = lane >> 5;
    int f = lane & 31;
    for (int n = wid; n < NN; n += nw){
        int m = cnt[n]; if (m > CAP) m = CAP;
        const ushort* sl = slots + (size_t)n * CAP;
        const ushort* hb = h + (size_t)b * NN * HF + f * 4;
        float ax = 0.f, ay = 0.f, az = 0.f, aww = 0.f;
        int i = 0;
        for (; i + 4 <= m; i += 4){
            ushort4 dd = *(const ushort4*)(sl + i);     // uniform 8B broadcast
            ushort4 u0 = *(const ushort4*)(hb + (size_t)dd.x * HF);
            ushort4 u1 = *(const ushort4*)(hb + (size_t)dd.y * HF);
            ushort4 u2 = *(const ushort4*)(hb + (size_t)dd.z * HF);
            ushort4 u3 = *(const ushort4*)(hb + (size_t)dd.w * HF);
            ax += bf2f(u0.x) + bf2f(u1.x) + bf2f(u2.x) + bf2f(u3.x);
            ay += bf2f(u0.y) + bf2f(u1.y) + bf2f(u2.y) + bf2f(u3.y);
            az += bf2f(u0.z) + bf2f(u1.z) + bf2f(u2.z) + bf2f(u3.z);
            aww += bf2f(u0.w) + bf2f(u1.w) + bf2f(u2.w) + bf2f(u3.w);
        }
        for (; i < m; ++i){
            ushort4 u = *(const ushort4*)(hb + (size_t)sl[i] * HF);
            ax += bf2f(u.x); ay += bf2f(u.y); az += bf2f(u.z); aww += bf2f(u.w);
        }
        float4 awv = *(const float4*)(aw + ((size_t)b * NN + n) * NH);
        out_f[((size_t)b * NN + n) * OUTF + f] =
            awv.x * ax + awv.y * ay + awv.z * az + awv.w * aww;
    }
}

// K4: overflow fix-up (normally empty). One wave per overflow edge, atomics.
__global__ void k_fix(const int* __restrict__ ei, const int* __restrict__ flags,
                      const int* __restrict__ ovf_cnt, const int* __restrict__ ovf_list,
                      const ushort* __restrict__ h, const float* __restrict__ aw,
                      float* __restrict__ out_f){
    int lane = threadIdx.x & 63;
    int wid  = (blockIdx.x * blockDim.x + threadIdx.x) >> 6;
    int nw   = (gridDim.x * blockDim.x) >> 6;
    int b = lane >> 5;
    int f = lane & 31;
    int M = *ovf_cnt; if (M > OVF_CAP) M = OVF_CAP;
    int f64 = flags[1];
    for (int i = wid; i < M; i += nw){
        int e = ovf_list[i];
        int s = get_src(ei, e, f64);
        int d = get_dst(ei, e, f64);
        float4 awv = *(const float4*)(aw + ((size_t)b * NN + s) * NH);
        ushort4 u = *(const ushort4*)(h + ((size_t)b * NN + d) * HF + f * 4);
        float acc = awv.x * bf2f(u.x) + awv.y * bf2f(u.y)
                  + awv.z * bf2f(u.z) + awv.w * bf2f(u.w);
        atomicAdd(&out_f[((size_t)b * NN + s) * OUTF + f], acc);
    }
}

extern "C" void kernel_launch(void* const* d_in, const int* in_sizes, int n_in,
                              void* d_out, int out_size, void* d_ws, size_t ws_size,
                              hipStream_t stream){
    const void* x = d_in[0]; const void* eiv = d_in[1];
    const void* W = d_in[2]; const void* a  = d_in[3];
    for (int i = 0; i < n_in; ++i){
        if      (in_sizes[i] == BB * NN * INF) x   = d_in[i];
        else if (in_sizes[i] == 2 * EE)        eiv = d_in[i];
        else if (in_sizes[i] == HF * INF)      W   = d_in[i];
        else if (in_sizes[i] == 2 * OUTF)      a   = d_in[i];
    }
    const int* ei = (const int*)eiv;
    float* out = (float*)d_out;    // output dtype: float32 (verified round 3)

    // Workspace (~15.5 MiB): flags | wbf | h | alpha_s | alpha_d | aw | last_e
    //                        | cnt | ovf_cnt | ovf_list | slots
    const size_t HN = (size_t)BB * NN * HF;
    char* p = (char*)d_ws;
    int*    flags    = (int*)p;                       p += 64;
    ushort* wbf      = (ushort*)p;                    p += 32768 * 2;
    ushort* h        = (ushort*)p;                    p += HN * 2;
    float*  alpha_s  = (float*)p;                     p += (size_t)BB * NN * NH * 4;
    float*  alpha_d  = (float*)p;                     p += (size_t)BB * NN * NH * 4;
    float*  aw       = (float*)p;                     p += (size_t)BB * NN * NH * 4;
    int*    last_e   = (int*)p;                       p += (size_t)NN * 4;
    int*    cnt      = (int*)p;                       p += (size_t)NN * 4;
    int*    ovf_cnt  = (int*)p;                       p += 64;
    int*    ovf_list = (int*)p;                       p += (size_t)OVF_CAP * 4;
    ushort* slots    = (ushort*)p;

    k_init <<<(NN + 255) / 256, 256, 0, stream>>>((const ushort*)x, ei, W, flags, wbf,
                                                  cnt, last_e, ovf_cnt);
    k_gemm <<<GEMM_BLOCKS + EDGE_BLOCKS, 256, 0, stream>>>(x, wbf, a, ei, flags, h,
                                                           alpha_s, alpha_d, last_e,
                                                           cnt, slots, ovf_cnt, ovf_list);
    k_aw   <<<(NN + 255) / 256, 256, 0, stream>>>(ei, flags, last_e, alpha_s, alpha_d, aw);
    k_agg  <<<2048, 256, 0, stream>>>(slots, cnt, h, aw, out);
    k_fix  <<<32, 256, 0, stream>>>(ei, flags, ovf_cnt, ovf_list, h, aw, out);
}